// Round 2
// baseline (1575.079 us; speedup 1.0000x reference)
//
#include <hip/hip_runtime.h>
#include <float.h>

// ---------------------------------------------------------------------------
// OnlineClustering: normalize -> GEMM (bf16 MFMA, epilogue computes
// M0 = exp(l/T - SHIFT0) in bf16 + first column sums) -> 2 fused
// rowsum+colsum passes -> final pass (assignments + CE loss).
//
// Sinkhorn factorization: M_final[s,k] = M0[s,k] * C[b,k] * R[b,s].
// Column-constant shifts cancel in the first column normalization, so a
// FIXED shift (SHIFT0) replaces the reference's per-column max. bf16 M0
// (134 MB) is L3-resident; relative error 0.2% ≪ threshold.
// Loss logits recovered as l = (ln(M0) + SHIFT0) * 0.07.
// ---------------------------------------------------------------------------

#define TT_INV 14.285714285714286f   // 1/0.07
#define TT_F   0.07f
#define TP_INV 8.333333333333334f    // 1/0.12
#define RATIO  0.5833333333f         // TP_INV/TT_INV = 0.07/0.12
#define SHIFT0 18.0f
#define SK_EPS 1e-8f

typedef short v8s __attribute__((ext_vector_type(8)));
typedef unsigned short vu8 __attribute__((ext_vector_type(8)));
typedef float v4f __attribute__((ext_vector_type(4)));

__device__ inline unsigned short f2bf(float f){          // RNE float->bf16
  unsigned u = __float_as_uint(f);
  u += 0x7FFFu + ((u >> 16) & 1u);
  return (unsigned short)(u >> 16);
}
__device__ inline float bf2f(unsigned short u){
  return __uint_as_float(((unsigned)u) << 16);
}

// block = 256 threads (4 waves)
__device__ inline float blockReduceSum(float v, float* sb){
  #pragma unroll
  for(int o = 32; o; o >>= 1) v += __shfl_down(v, o);
  __syncthreads();
  if((threadIdx.x & 63) == 0) sb[threadIdx.x >> 6] = v;
  __syncthreads();
  return (sb[0] + sb[1]) + (sb[2] + sb[3]);
}

__device__ inline void gl_lds16(const void* g, void* l){
  __builtin_amdgcn_global_load_lds(
      (const __attribute__((address_space(1))) void*)g,
      (__attribute__((address_space(3))) void*)l, 16, 0, 0);
}

// -------------------- init small buffers --------------------
__global__ __launch_bounds__(256) void init_k(float* __restrict__ tbuf,
                                              float* __restrict__ Cb,
                                              float* __restrict__ Rb,
                                              float* __restrict__ lossacc){
  int i = blockIdx.x * 256 + threadIdx.x;   // grid covers 262144
  tbuf[i] = 0.f;
  Cb[i] = 1.f;
  if(i < 8192) Rb[i] = 1.f;
  if(i == 0) lossacc[0] = 0.f;
}

// -------------------- normalize x rows, cast bf16 --------------------
__global__ __launch_bounds__(256) void norm_x_k(const float* __restrict__ x,
                                                unsigned short* __restrict__ xb){
  const int row = blockIdx.x, t = threadIdx.x;
  const float4 v = ((const float4*)(x + (size_t)row * 1024))[t];
  __shared__ float sb[4];
  float ss = v.x*v.x + v.y*v.y + v.z*v.z + v.w*v.w;
  float tot = blockReduceSum(ss, sb);
  float sc = 1.0f / fmaxf(sqrtf(tot), 1e-7f);
  ushort4 o = { f2bf(v.x*sc), f2bf(v.y*sc), f2bf(v.z*sc), f2bf(v.w*sc) };
  ((ushort4*)(xb + (size_t)row * 1024))[t] = o;
}

// -------------------- cast W bf16 --------------------
__global__ __launch_bounds__(256) void conv_w_k(const float* __restrict__ W,
                                                unsigned short* __restrict__ Wb){
  const size_t i = (size_t)blockIdx.x * 256 + threadIdx.x;
  const float4 v = ((const float4*)W)[i];
  ushort4 o = { f2bf(v.x), f2bf(v.y), f2bf(v.z), f2bf(v.w) };
  ((ushort4*)Wb)[i] = o;
}

// -------------------- bf16 GEMM + M0 epilogue + colsum1 --------------------
// 128x128 tile, BK=32, 4 waves each 64x64. LDS k-chunk placement XOR-swizzled
// (kc = o ^ ((r>>1)&3)) so fragment ds_read_b128s hit all 8 bank-groups
// (2-way aliasing = free) while global_load_lds writes stay lane-contiguous.
__global__ __launch_bounds__(256) void gemm_k(const unsigned short* __restrict__ A,
                                              const unsigned short* __restrict__ B,
                                              unsigned short* __restrict__ M0out,
                                              float* __restrict__ t1){
  __shared__ __align__(16) short As[128 * 32];
  __shared__ __align__(16) short Bs[128 * 32];
  const int t = threadIdx.x;
  const int L = t & 63, w = t >> 6;
  const int wm = w >> 1, wn = w & 1;
  const int quad = L >> 4, lr = L & 15;
  const int mb = blockIdx.y * 128, n0 = blockIdx.x * 128;

  v4f acc[4][4];
  #pragma unroll
  for(int i = 0; i < 4; i++)
    #pragma unroll
    for(int j = 0; j < 4; j++) acc[i][j] = (v4f){0.f, 0.f, 0.f, 0.f};

  // staging: 512 16B-chunks per tile, 2 per thread; swizzled k-chunk fetch
  const int c0 = t, c1 = t + 256;
  const int r0 = c0 >> 2, k0 = (c0 & 3) ^ ((r0 >> 1) & 3);
  const int r1 = c1 >> 2, k1 = (c1 & 3) ^ ((r1 >> 1) & 3);
  const unsigned short* gA0 = A + (size_t)(mb + r0) * 1024 + k0 * 8;
  const unsigned short* gA1 = A + (size_t)(mb + r1) * 1024 + k1 * 8;
  const unsigned short* gB0 = B + (size_t)(n0 + r0) * 1024 + k0 * 8;
  const unsigned short* gB1 = B + (size_t)(n0 + r1) * 1024 + k1 * 8;
  short* lA0 = &As[c0 * 8]; short* lA1 = &As[c1 * 8];
  short* lB0 = &Bs[c0 * 8]; short* lB1 = &Bs[c1 * 8];

  const int swz = (lr >> 1) & 3;
  for(int kt = 0; kt < 32; ++kt){
    __syncthreads();
    const int ko = kt * 32;
    gl_lds16(gA0 + ko, lA0);
    gl_lds16(gA1 + ko, lA1);
    gl_lds16(gB0 + ko, lB0);
    gl_lds16(gB1 + ko, lB1);
    __syncthreads();
    v8s af[4], bf[4];
    #pragma unroll
    for(int mi = 0; mi < 4; mi++)
      af[mi] = *(const v8s*)&As[(wm*64 + mi*16 + lr) * 32 + (quad ^ swz) * 8];
    #pragma unroll
    for(int ni = 0; ni < 4; ni++)
      bf[ni] = *(const v8s*)&Bs[(wn*64 + ni*16 + lr) * 32 + (quad ^ swz) * 8];
    #pragma unroll
    for(int mi = 0; mi < 4; mi++)
      #pragma unroll
      for(int ni = 0; ni < 4; ni++)
        acc[mi][ni] = __builtin_amdgcn_mfma_f32_16x16x32_bf16(af[mi], bf[ni], acc[mi][ni], 0, 0, 0);
  }
  // epilogue: M0 = exp(l*TT_INV - SHIFT0) -> bf16; per-column partial sums
  // C/D layout: col = lane&15, row = quad*4 + reg
  const int bb = blockIdx.y >> 1;            // batch (128-row tile -> by>>1)
  float colp[4] = {0.f, 0.f, 0.f, 0.f};
  #pragma unroll
  for(int mi = 0; mi < 4; mi++){
    const int row = mb + wm*64 + mi*16 + quad*4;
    #pragma unroll
    for(int ni = 0; ni < 4; ni++){
      const int col = n0 + wn*64 + ni*16 + lr;
      #pragma unroll
      for(int r = 0; r < 4; r++){
        const float m0v = __expf(fmaf(acc[mi][ni][r], TT_INV, -SHIFT0));
        colp[ni] += m0v;
        M0out[(size_t)(row + r) * 8192 + col] = f2bf(m0v);
      }
    }
  }
  #pragma unroll
  for(int ni = 0; ni < 4; ni++){
    float v = colp[ni];
    v += __shfl_xor(v, 16);
    v += __shfl_xor(v, 32);
    if(quad == 0)
      atomicAdd(t1 + (size_t)bb * 8192 + (n0 + wn*64 + ni*16 + lr), v);
  }
}

// -------------------- C update (and reset t for next iter) --------------------
__global__ __launch_bounds__(256) void updC_k(float* __restrict__ Cb,
                                              float* __restrict__ tbuf){
  const int i = blockIdx.x * 256 + threadIdx.x;
  const float c = Cb[i], tt = tbuf[i];
  Cb[i] = c / (c * tt + SK_EPS);
  tbuf[i] = 0.f;
}

// -------------------- fused rowsum_i + colsum_{i+1} --------------------
// block = 8 rows x 8192 cols. Sweep1: w = sum_k M0*C -> R_new (per row).
// Sweep2 (L3 re-read): t_next[k] += sum_r M0*R_new, 8 atomics/thread/chunk.
__global__ __launch_bounds__(256) void sk_pass_k(const unsigned short* __restrict__ M0,
                                                 const float* __restrict__ Cb,
                                                 float* __restrict__ Rb,
                                                 float* __restrict__ tnext){
  const int blk = blockIdx.x;            // 0..1023
  const int b = blk >> 5;
  const int row0 = blk * 8;
  const int t = threadIdx.x;
  const float* Cp = Cb + (size_t)b * 8192;

  float racc[8];
  #pragma unroll
  for(int r = 0; r < 8; r++) racc[r] = 0.f;

  #pragma unroll
  for(int cc = 0; cc < 4; cc++){
    const int col = cc * 2048 + t * 8;
    float cv[8];
    *(float4*)&cv[0] = *(const float4*)(Cp + col);
    *(float4*)&cv[4] = *(const float4*)(Cp + col + 4);
    #pragma unroll
    for(int r = 0; r < 8; r++){
      const vu8 m = *(const vu8*)(M0 + (size_t)(row0 + r) * 8192 + col);
      float s = 0.f;
      #pragma unroll
      for(int j = 0; j < 8; j++) s += bf2f(m[j]) * cv[j];
      racc[r] += s;
    }
  }

  __shared__ float red[8][256];
  __shared__ float rnewS[8];
  #pragma unroll
  for(int r = 0; r < 8; r++) red[r][t] = racc[r];
  __syncthreads();
  const int w = t >> 6, lane = t & 63;
  #pragma unroll
  for(int rr = 0; rr < 2; rr++){
    const int r = w * 2 + rr;
    float v = (red[r][lane] + red[r][lane+64]) + (red[r][lane+128] + red[r][lane+192]);
    #pragma unroll
    for(int o = 32; o; o >>= 1) v += __shfl_down(v, o);
    if(lane == 0){
      const float R = Rb[row0 + r];
      const float Rn = R / (R * v + SK_EPS);
      rnewS[r] = Rn;
      Rb[row0 + r] = Rn;
    }
  }
  __syncthreads();
  float rn[8];
  #pragma unroll
  for(int r = 0; r < 8; r++) rn[r] = rnewS[r];

  #pragma unroll
  for(int cc = 0; cc < 4; cc++){
    const int col = cc * 2048 + t * 8;
    float cacc[8];
    #pragma unroll
    for(int j = 0; j < 8; j++) cacc[j] = 0.f;
    #pragma unroll
    for(int r = 0; r < 8; r++){
      const vu8 m = *(const vu8*)(M0 + (size_t)(row0 + r) * 8192 + col);
      #pragma unroll
      for(int j = 0; j < 8; j++) cacc[j] += bf2f(m[j]) * rn[r];
    }
    float* tp = tnext + (size_t)b * 8192 + col;
    #pragma unroll
    for(int j = 0; j < 8; j++) atomicAdd(tp + j, cacc[j]);
  }
}

// -------------------- final: rowsum_3 -> R3 -> assignments + loss ----------
__global__ __launch_bounds__(256) void final_k(const unsigned short* __restrict__ M0,
                                               const float* __restrict__ Cb,
                                               const float* __restrict__ Rb,
                                               float* __restrict__ out,
                                               float* __restrict__ lossacc){
  const int blk = blockIdx.x;
  const int b = blk >> 5;
  const int row0 = blk * 8;
  const int t = threadIdx.x;
  const float* Cp = Cb + (size_t)b * 8192;

  float racc[8], rmax[8];
  #pragma unroll
  for(int r = 0; r < 8; r++){ racc[r] = 0.f; rmax[r] = 0.f; }

  #pragma unroll
  for(int cc = 0; cc < 4; cc++){
    const int col = cc * 2048 + t * 8;
    float cv[8];
    *(float4*)&cv[0] = *(const float4*)(Cp + col);
    *(float4*)&cv[4] = *(const float4*)(Cp + col + 4);
    #pragma unroll
    for(int r = 0; r < 8; r++){
      const vu8 m = *(const vu8*)(M0 + (size_t)(row0 + r) * 8192 + col);
      float s = 0.f, mx = 0.f;
      #pragma unroll
      for(int j = 0; j < 8; j++){
        const float f = bf2f(m[j]);
        s += f * cv[j];
        mx = fmaxf(mx, f);
      }
      racc[r] += s;
      rmax[r] = fmaxf(rmax[r], mx);
    }
  }

  __shared__ float red[8][256];
  __shared__ float rnewS[8], lgmS[8];
  const int w = t >> 6, lane = t & 63;
  // row sums -> R3
  #pragma unroll
  for(int r = 0; r < 8; r++) red[r][t] = racc[r];
  __syncthreads();
  #pragma unroll
  for(int rr = 0; rr < 2; rr++){
    const int r = w * 2 + rr;
    float v = (red[r][lane] + red[r][lane+64]) + (red[r][lane+128] + red[r][lane+192]);
    #pragma unroll
    for(int o = 32; o; o >>= 1) v += __shfl_down(v, o);
    if(lane == 0){
      const float R = Rb[row0 + r];
      rnewS[r] = R / (R * v + SK_EPS);
    }
  }
  __syncthreads();
  // row maxes -> ln(m0max)
  #pragma unroll
  for(int r = 0; r < 8; r++) red[r][t] = rmax[r];
  __syncthreads();
  #pragma unroll
  for(int rr = 0; rr < 2; rr++){
    const int r = w * 2 + rr;
    float v = fmaxf(fmaxf(red[r][lane], red[r][lane+64]),
                    fmaxf(red[r][lane+128], red[r][lane+192]));
    #pragma unroll
    for(int o = 32; o; o >>= 1) v = fmaxf(v, __shfl_down(v, o));
    if(lane == 0) lgmS[r] = __logf(v);
  }
  __syncthreads();
  float rn[8], lgm[8];
  #pragma unroll
  for(int r = 0; r < 8; r++){ rn[r] = rnewS[r]; lgm[r] = lgmS[r]; }

  float pe[8], sT[8], sTP[8];
  #pragma unroll
  for(int r = 0; r < 8; r++){ pe[r] = 0.f; sT[r] = 0.f; sTP[r] = 0.f; }

  #pragma unroll
  for(int cc = 0; cc < 4; cc++){
    const int col = cc * 2048 + t * 8;
    float cv[8];
    *(float4*)&cv[0] = *(const float4*)(Cp + col);
    *(float4*)&cv[4] = *(const float4*)(Cp + col + 4);
    #pragma unroll
    for(int r = 0; r < 8; r++){
      const vu8 m = *(const vu8*)(M0 + (size_t)(row0 + r) * 8192 + col);
      float o8[8];
      #pragma unroll
      for(int j = 0; j < 8; j++){
        const float m0v = bf2f(m[j]);
        const float a = m0v * cv[j] * rn[r];
        o8[j] = a;
        const float lg = __logf(fmaxf(m0v, 1e-37f));
        pe[r]  += __expf((lg - lgm[r]) * RATIO);
        sT[r]  += a;
        sTP[r] += a * ((lg + SHIFT0) * TT_F);   // a * l
      }
      float* op = out + (size_t)(row0 + r) * 8192 + col;
      *(float4*)op       = *(float4*)&o8[0];
      *(float4*)(op + 4) = *(float4*)&o8[4];
    }
  }

  // loss reductions
  __shared__ float peS[8], sTS[8], sTPS[8];
  #pragma unroll
  for(int r = 0; r < 8; r++) red[r][t] = pe[r];
  __syncthreads();
  #pragma unroll
  for(int rr = 0; rr < 2; rr++){
    const int r = w * 2 + rr;
    float v = (red[r][lane] + red[r][lane+64]) + (red[r][lane+128] + red[r][lane+192]);
    #pragma unroll
    for(int o = 32; o; o >>= 1) v += __shfl_down(v, o);
    if(lane == 0) peS[r] = v;
  }
  __syncthreads();
  #pragma unroll
  for(int r = 0; r < 8; r++) red[r][t] = sT[r];
  __syncthreads();
  #pragma unroll
  for(int rr = 0; rr < 2; rr++){
    const int r = w * 2 + rr;
    float v = (red[r][lane] + red[r][lane+64]) + (red[r][lane+128] + red[r][lane+192]);
    #pragma unroll
    for(int o = 32; o; o >>= 1) v += __shfl_down(v, o);
    if(lane == 0) sTS[r] = v;
  }
  __syncthreads();
  #pragma unroll
  for(int r = 0; r < 8; r++) red[r][t] = sTP[r];
  __syncthreads();
  #pragma unroll
  for(int rr = 0; rr < 2; rr++){
    const int r = w * 2 + rr;
    float v = (red[r][lane] + red[r][lane+64]) + (red[r][lane+128] + red[r][lane+192]);
    #pragma unroll
    for(int o = 32; o; o >>= 1) v += __shfl_down(v, o);
    if(lane == 0) sTPS[r] = v;
  }
  __syncthreads();
  if(t == 0){
    float c = 0.f;
    #pragma unroll
    for(int r = 0; r < 8; r++){
      const float Lmax = (lgm[r] + SHIFT0) * TT_F;       // row max logit
      const float lse = Lmax * TP_INV + __logf(peS[r]);
      c += TP_INV * sTPS[r] - lse * sTS[r];
    }
    atomicAdd(lossacc, c);
  }
}

__global__ void finscale_k(const float* __restrict__ lossacc, float* __restrict__ dst){
  dst[0] = -lossacc[0] * (1.0f / 8192.0f);
}

// ---------------------------------------------------------------------------
extern "C" void kernel_launch(void* const* d_in, const int* in_sizes, int n_in,
                              void* d_out, int out_size, void* d_ws, size_t ws_size,
                              hipStream_t stream){
  const float* x = (const float*)d_in[0];   // [32,256,1024]
  const float* W = (const float*)d_in[1];   // [8192,1024]
  float* out = (float*)d_out;               // 32*256*8192 assignments + 1 loss

  char* ws = (char*)d_ws;
  unsigned short* xb  = (unsigned short*)(ws);                 // 16 MB bf16
  unsigned short* Wb  = (unsigned short*)(ws + 16777216);      // 16 MB bf16
  unsigned short* M0b = (unsigned short*)(ws + 33554432);      // 128 MB bf16
  float* tbuf    = (float*)(ws + 167772160);                   // 1 MB
  float* Cb      = (float*)(ws + 168820736);                   // 1 MB
  float* Rb      = (float*)(ws + 169869312);                   // 32 KB
  float* lossacc = (float*)(ws + 169902080);                   // 4 B

  init_k  <<<1024, 256, 0, stream>>>(tbuf, Cb, Rb, lossacc);
  norm_x_k<<<8192, 256, 0, stream>>>(x, xb);
  conv_w_k<<<8192, 256, 0, stream>>>(W, Wb);
  gemm_k  <<<dim3(64, 64), 256, 0, stream>>>(xb, Wb, M0b, tbuf); // M0 + t1
  updC_k  <<<1024, 256, 0, stream>>>(Cb, tbuf);                  // C1
  sk_pass_k<<<1024, 256, 0, stream>>>(M0b, Cb, Rb, tbuf);        // R1, t2
  updC_k  <<<1024, 256, 0, stream>>>(Cb, tbuf);                  // C2
  sk_pass_k<<<1024, 256, 0, stream>>>(M0b, Cb, Rb, tbuf);        // R2, t3
  updC_k  <<<1024, 256, 0, stream>>>(Cb, tbuf);                  // C3
  final_k <<<1024, 256, 0, stream>>>(M0b, Cb, Rb, out, lossacc); // R3, out, loss
  finscale_k<<<1, 1, 0, stream>>>(lossacc, out + (size_t)(out_size - 1));
}